// Round 1
// baseline (152.171 us; speedup 1.0000x reference)
//
#include <hip/hip_runtime.h>
#include <hip/hip_bf16.h>

// LRGCN_Batch: the reference returns ONLY h2. The entire _relation() path
// (G1/G2/B1/B2 matmuls, gamma/beta, r, and the w1-weighted mean_x) is dead.
// Live computation:
//   h1 = elu( (mean_k x[adj1_idx[:,1:]] * adj1_w2[:,1:,None]) @ W1 )
//   h2 =      (mean_k h1[adj2_idx[:,1:]] * adj2_w2[:,1:,None]) @ W2
// N=50000, K=16, NFEAT=NHID=128, NCLASS=64. All fp32 (no MFMA: no fp32 MFMA
// on CDNA4, and bf16 would risk the ~7.7e-4 absolute threshold).

#define NN     50000
#define KNBR   16
#define NFEAT  128
#define NHID   128
#define NCLASS 64

// ---------------- layer 1: gather-mean + matmul(128x128) + elu --------------
// block = 128 threads, NPB nodes per block.
// Phase A: stage (idx, w) for NPB*K = 128 neighbors in LDS (1 load/thread).
// Phase B: thread t computes e[n][t] = (1/K) sum_k w[n][k]*x[idx[n][k]*128+t]
//          (coalesced 512B row reads; x is 25.6MB -> L2/L3 resident).
// Phase C: thread t computes h1[n][t] for all NPB nodes:
//          loop f: wv = W1[f][t] (coalesced, read ONCE per NPB nodes),
//          acc[n] += e[n][f] * wv  (e broadcast from LDS).
template <int NPB>
__global__ __launch_bounds__(128) void lrgcn_layer1(
    const float* __restrict__ x, const int* __restrict__ idx,
    const float* __restrict__ w, const float* __restrict__ W1,
    float* __restrict__ h1) {
  __shared__ float e_s[NPB][NFEAT];
  __shared__ int   idx_s[NPB][KNBR];
  __shared__ float w_s[NPB][KNBR];

  const int t  = threadIdx.x;        // 0..127
  const int n0 = blockIdx.x * NPB;

  {  // NPB*K == 128 == blockDim.x
    const int node = t >> 4, k = t & 15;
    const int g = (n0 + node) * (KNBR + 1) + 1 + k;
    idx_s[node][k] = idx[g];
    w_s[node][k]   = w[g];
  }
  __syncthreads();

  for (int n = 0; n < NPB; ++n) {
    float acc = 0.f;
#pragma unroll
    for (int k = 0; k < KNBR; ++k) {
      acc += w_s[n][k] * x[(long)idx_s[n][k] * NFEAT + t];
    }
    e_s[n][t] = acc * (1.0f / KNBR);
  }
  __syncthreads();

  float acc[NPB];
#pragma unroll
  for (int n = 0; n < NPB; ++n) acc[n] = 0.f;
  for (int f = 0; f < NFEAT; ++f) {
    const float wv = W1[f * NHID + t];
#pragma unroll
    for (int n = 0; n < NPB; ++n) acc[n] += e_s[n][f] * wv;
  }
#pragma unroll
  for (int n = 0; n < NPB; ++n) {
    float v = acc[n];
    v = v > 0.f ? v : expm1f(v);  // jax.nn.elu uses expm1
    h1[(long)(n0 + n) * NHID + t] = v;
  }
}

// ---------------- layer 2: gather-mean + matmul(128x64) ---------------------
// Same structure; matmul has 64 outputs, so the 128 threads split:
// threads 0..63 handle nodes 0..NPB/2-1, threads 64..127 nodes NPB/2..NPB-1,
// each computing output column (t & 63). Keeps all lanes busy.
template <int NPB>
__global__ __launch_bounds__(128) void lrgcn_layer2(
    const float* __restrict__ h1, const int* __restrict__ idx,
    const float* __restrict__ w, const float* __restrict__ W2,
    float* __restrict__ out) {
  __shared__ float e_s[NPB][NHID];
  __shared__ int   idx_s[NPB][KNBR];
  __shared__ float w_s[NPB][KNBR];

  const int t  = threadIdx.x;
  const int n0 = blockIdx.x * NPB;

  {
    const int node = t >> 4, k = t & 15;
    const int g = (n0 + node) * (KNBR + 1) + 1 + k;
    idx_s[node][k] = idx[g];
    w_s[node][k]   = w[g];
  }
  __syncthreads();

  for (int n = 0; n < NPB; ++n) {
    float acc = 0.f;
#pragma unroll
    for (int k = 0; k < KNBR; ++k) {
      acc += w_s[n][k] * h1[(long)idx_s[n][k] * NHID + t];
    }
    e_s[n][t] = acc * (1.0f / KNBR);
  }
  __syncthreads();

  constexpr int NH = NPB / 2;
  const int c  = t & 63;
  const int nh = (t >> 6) * NH;
  float acc[NH];
#pragma unroll
  for (int n = 0; n < NH; ++n) acc[n] = 0.f;
  for (int f = 0; f < NHID; ++f) {
    const float wv = W2[f * NCLASS + c];
#pragma unroll
    for (int n = 0; n < NH; ++n) acc[n] += e_s[nh + n][f] * wv;
  }
#pragma unroll
  for (int n = 0; n < NH; ++n) {
    out[(long)(n0 + nh + n) * NCLASS + c] = acc[n];
  }
}

extern "C" void kernel_launch(void* const* d_in, const int* in_sizes, int n_in,
                              void* d_out, int out_size, void* d_ws,
                              size_t ws_size, hipStream_t stream) {
  // setup_inputs order:
  // 0:x 1:adj1_idx 2:adj1_w1(dead) 3:adj1_w2 4:adj2_idx 5:adj2_w1(dead)
  // 6:adj2_w2 7:W1 8:W2 9..18: relation params (ALL dead)
  const float* x    = (const float*)d_in[0];
  const int*   a1i  = (const int*)d_in[1];
  const float* a1w  = (const float*)d_in[3];
  const int*   a2i  = (const int*)d_in[4];
  const float* a2w  = (const float*)d_in[6];
  const float* W1   = (const float*)d_in[7];
  const float* W2   = (const float*)d_in[8];
  float*       out  = (float*)d_out;
  float*       h1   = (float*)d_ws;  // needs NN*NHID*4 = 25.6 MB

  constexpr int NPB = 8;  // 50000 % 8 == 0 -> 6250 blocks
  lrgcn_layer1<NPB><<<NN / NPB, 128, 0, stream>>>(x, a1i, a1w, W1, h1);
  lrgcn_layer2<NPB><<<NN / NPB, 128, 0, stream>>>(h1, a2i, a2w, W2, out);
}

// Round 2
// 128.350 us; speedup vs baseline: 1.1856x; 1.1856x over previous
//
#include <hip/hip_runtime.h>
#include <hip/hip_bf16.h>

// LRGCN_Batch: the reference returns ONLY h2 -> the _relation() path is dead.
// Live computation:
//   h1 = elu( (mean_k x[adj1_idx[:,1:]] * adj1_w2[:,1:,None]) @ W1 )
//   h2 =      (mean_k h1[adj2_idx[:,1:]] * adj2_w2[:,1:,None]) @ W2
// N=50000, K=16, NFEAT=NHID=128, NCLASS=64. Pure fp32 (no fp32 MFMA on CDNA4;
// bf16 inputs would risk the ~7.7e-4 abs threshold — fp32 path is at 6e-5).
//
// R2 change vs R1: float4 gathers (4x fewer VMEM ops + addr VALU),
// NPB 8->16, block 128->256 (2x W reuse, more waves for latency hiding).

#define NN     50000
#define KNBR   16
#define NFEAT  128
#define NHID   128
#define NCLASS 64

// block = 256 threads, NPB = 16 nodes/block -> NPB*K = 256 (idx,w) pairs.
// Phase A: 1 (idx,w) pair per thread into LDS.
// Phase B: 8 groups of 32 lanes; group g handles nodes {2g, 2g+1}. For each
//          node, 16 float4 gathers x4[idx*32 + lane] accumulated in regs.
//          One wave-instr = 64 lanes x 16B = 1KB (two full rows) coalesced.
// Phase C: per-node matmul. Threads own (node_half, out_col); W row read once
//          per f, reused across 8 nodes from registers.
template <int NPB>
__global__ __launch_bounds__(256, 4) void lrgcn_layer1(
    const float* __restrict__ x, const int* __restrict__ idx,
    const float* __restrict__ w, const float* __restrict__ W1,
    float* __restrict__ h1) {
  __shared__ float e_s[NPB][NFEAT];
  __shared__ int   idx_s[NPB][KNBR];
  __shared__ float w_s[NPB][KNBR];

  const int t  = threadIdx.x;        // 0..255
  const int n0 = blockIdx.x * NPB;

  {  // NPB*K == 256 == blockDim.x
    const int node = t >> 4, k = t & 15;
    const int g = (n0 + node) * (KNBR + 1) + 1 + k;
    idx_s[node][k] = idx[g];
    w_s[node][k]   = w[g];
  }
  __syncthreads();

  const float4* __restrict__ x4 = (const float4*)x;
  {
    const int grp = t >> 5, l = t & 31;  // 8 groups x 32 lanes
#pragma unroll
    for (int i = 0; i < NPB / 8; ++i) {  // 2 nodes per group
      const int n = grp * (NPB / 8) + i;
      float ax = 0.f, ay = 0.f, az = 0.f, aw = 0.f;
#pragma unroll
      for (int k = 0; k < KNBR; ++k) {
        const float4 v  = x4[idx_s[n][k] * (NFEAT / 4) + l];
        const float  wv = w_s[n][k];
        ax += wv * v.x; ay += wv * v.y; az += wv * v.z; aw += wv * v.w;
      }
      float4 r;
      r.x = ax * (1.f / KNBR); r.y = ay * (1.f / KNBR);
      r.z = az * (1.f / KNBR); r.w = aw * (1.f / KNBR);
      *reinterpret_cast<float4*>(&e_s[n][l * 4]) = r;
    }
  }
  __syncthreads();

  {  // matmul: half = t>>7 owns nodes half*8..half*8+7, col = t&127
    const int c = t & 127, half = t >> 7;
    float acc[NPB / 2];
#pragma unroll
    for (int n = 0; n < NPB / 2; ++n) acc[n] = 0.f;
    for (int f = 0; f < NFEAT; ++f) {
      const float wv = W1[f * NHID + c];
#pragma unroll
      for (int n = 0; n < NPB / 2; ++n)
        acc[n] += e_s[half * (NPB / 2) + n][f] * wv;
    }
#pragma unroll
    for (int n = 0; n < NPB / 2; ++n) {
      float v = acc[n];
      v = v > 0.f ? v : expm1f(v);  // jax.nn.elu
      h1[(n0 + half * (NPB / 2) + n) * NHID + c] = v;
    }
  }
}

template <int NPB>
__global__ __launch_bounds__(256, 4) void lrgcn_layer2(
    const float* __restrict__ h1, const int* __restrict__ idx,
    const float* __restrict__ w, const float* __restrict__ W2,
    float* __restrict__ out) {
  __shared__ float e_s[NPB][NHID];
  __shared__ int   idx_s[NPB][KNBR];
  __shared__ float w_s[NPB][KNBR];

  const int t  = threadIdx.x;
  const int n0 = blockIdx.x * NPB;

  {
    const int node = t >> 4, k = t & 15;
    const int g = (n0 + node) * (KNBR + 1) + 1 + k;
    idx_s[node][k] = idx[g];
    w_s[node][k]   = w[g];
  }
  __syncthreads();

  const float4* __restrict__ h4 = (const float4*)h1;
  {
    const int grp = t >> 5, l = t & 31;
#pragma unroll
    for (int i = 0; i < NPB / 8; ++i) {
      const int n = grp * (NPB / 8) + i;
      float ax = 0.f, ay = 0.f, az = 0.f, aw = 0.f;
#pragma unroll
      for (int k = 0; k < KNBR; ++k) {
        const float4 v  = h4[idx_s[n][k] * (NHID / 4) + l];
        const float  wv = w_s[n][k];
        ax += wv * v.x; ay += wv * v.y; az += wv * v.z; aw += wv * v.w;
      }
      float4 r;
      r.x = ax * (1.f / KNBR); r.y = ay * (1.f / KNBR);
      r.z = az * (1.f / KNBR); r.w = aw * (1.f / KNBR);
      *reinterpret_cast<float4*>(&e_s[n][l * 4]) = r;
    }
  }
  __syncthreads();

  {  // matmul: quarter q = t>>6 owns nodes q*4..q*4+3, col = t&63
    const int c = t & 63, q = t >> 6;
    float acc[NPB / 4];
#pragma unroll
    for (int n = 0; n < NPB / 4; ++n) acc[n] = 0.f;
    for (int f = 0; f < NHID; ++f) {
      const float wv = W2[f * NCLASS + c];
#pragma unroll
      for (int n = 0; n < NPB / 4; ++n)
        acc[n] += e_s[q * (NPB / 4) + n][f] * wv;
    }
#pragma unroll
    for (int n = 0; n < NPB / 4; ++n)
      out[(n0 + q * (NPB / 4) + n) * NCLASS + c] = acc[n];
  }
}

extern "C" void kernel_launch(void* const* d_in, const int* in_sizes, int n_in,
                              void* d_out, int out_size, void* d_ws,
                              size_t ws_size, hipStream_t stream) {
  // 0:x 1:adj1_idx 2:adj1_w1(dead) 3:adj1_w2 4:adj2_idx 5:adj2_w1(dead)
  // 6:adj2_w2 7:W1 8:W2 9..18: relation params (ALL dead)
  const float* x   = (const float*)d_in[0];
  const int*   a1i = (const int*)d_in[1];
  const float* a1w = (const float*)d_in[3];
  const int*   a2i = (const int*)d_in[4];
  const float* a2w = (const float*)d_in[6];
  const float* W1  = (const float*)d_in[7];
  const float* W2  = (const float*)d_in[8];
  float*       out = (float*)d_out;
  float*       h1  = (float*)d_ws;  // NN*NHID*4 = 25.6 MB

  constexpr int NPB = 16;  // 50000 / 16 = 3125 blocks
  lrgcn_layer1<NPB><<<NN / NPB, 256, 0, stream>>>(x, a1i, a1w, W1, h1);
  lrgcn_layer2<NPB><<<NN / NPB, 256, 0, stream>>>(h1, a2i, a2w, W2, out);
}